// Round 1
// baseline (627.916 us; speedup 1.0000x reference)
//
#include <hip/hip_runtime.h>

#define Bsz 256
#define Ssz 2048
#define Isz 32
#define Hsz 18

__device__ __forceinline__ float tanh_fast(float x) {
    // tanh(x) = 1 - 2/(e^{2x}+1); saturates correctly at +/-inf via v_exp/v_rcp
    float t = __expf(2.0f * x);
    float r = __builtin_amdgcn_rcpf(t + 1.0f);
    return fmaf(-2.0f, r, 1.0f);
}

// K1: xw0T[b][i][t] = sum_k input[b][t][k] * Wih0[i][k] + bih0[i] + bhh0[i]
__global__ __launch_bounds__(256) void input_gemm(
    const float* __restrict__ x,
    const float* __restrict__ Wih0,
    const float* __restrict__ bih0,
    const float* __restrict__ bhh0,
    float* __restrict__ xw0T)
{
    int blk = blockIdx.x;                  // 2048 blocks
    int b = blk >> 3;
    int t = ((blk & 7) << 8) | threadIdx.x;
    const float4* xp = (const float4*)(x + ((size_t)b * Ssz + (size_t)t) * Isz);
    float4 xv[8];
#pragma unroll
    for (int k = 0; k < 8; ++k) xv[k] = xp[k];
    float* op = xw0T + (size_t)b * (Hsz * Ssz) + t;
#pragma unroll
    for (int ii = 0; ii < Hsz; ++ii) {
        float acc = bih0[ii] + bhh0[ii];
#pragma unroll
        for (int k = 0; k < 8; ++k) {
            float4 w = *(const float4*)(Wih0 + ii * Isz + k * 4);
            acc = fmaf(xv[k].x, w.x, acc);
            acc = fmaf(xv[k].y, w.y, acc);
            acc = fmaf(xv[k].z, w.z, acc);
            acc = fmaf(xv[k].w, w.w, acc);
        }
        op[(size_t)ii * Ssz] = acc;
    }
}

// K2: pipelined 3-layer scan as a 54-wide recurrence. One wave per batch.
// Lane r = 18*g + i owns (layer g, unit i). State exchanged via LDS each tick.
// Group g at tick T computes h_g[t = T - g].
__global__ __launch_bounds__(64) void rnn_scan(
    const float* __restrict__ xw0T,
    const float* __restrict__ hidden,
    const float* __restrict__ Whh0,
    const float* __restrict__ Wih1, const float* __restrict__ bih1,
    const float* __restrict__ Whh1, const float* __restrict__ bhh1,
    const float* __restrict__ Wih2, const float* __restrict__ bih2,
    const float* __restrict__ Whh2, const float* __restrict__ bhh2,
    float* __restrict__ h2T,
    float* __restrict__ hid_out)
{
    const int b = blockIdx.x;
    const int r = threadIdx.x;
    const int g = (r < 18) ? 0 : (r < 36) ? 1 : (r < 54) ? 2 : 3;
    const int i = r - g * 18;
    const bool lane_active = (g < 3);

    // group stride 36 words (144B): group bases land on distinct bank quads,
    // float4 alignment preserved (144 % 16 == 0).
    __shared__ __align__(16) float sbuf[176];
    for (int k = r; k < 176; k += 64) sbuf[k] = 0.0f;

    float wh[Hsz], wx[Hsz];
    float econst = 0.0f;
    float h = 0.0f;
    if (lane_active) {
        const float* Whh = (g == 0) ? Whh0 : (g == 1) ? Whh1 : Whh2;
#pragma unroll
        for (int j = 0; j < Hsz; ++j) wh[j] = Whh[i * Hsz + j];
        if (g >= 1) {
            const float* Wih = (g == 1) ? Wih1 : Wih2;
            const float* bi  = (g == 1) ? bih1 : bih2;
            const float* bh  = (g == 1) ? bhh1 : bhh2;
#pragma unroll
            for (int j = 0; j < Hsz; ++j) wx[j] = Wih[i * Hsz + j];
            econst = bi[i] + bh[i];
        } else {
#pragma unroll
            for (int j = 0; j < Hsz; ++j) wx[j] = 0.0f;
        }
        h = hidden[(g * Bsz + b) * Hsz + i];
    } else {
#pragma unroll
        for (int j = 0; j < Hsz; ++j) { wh[j] = 0.0f; wx[j] = 0.0f; }
    }

    const int slot  = 36 + 36 * g + i;   // g==3 dump region 144..153 (stays 0)
    const int xbase = 36 * g;            // previous group's state (g0 reads zeros)
    const int hbase = 36 * g + 36;       // own group's state

    sbuf[slot] = h;
    __builtin_amdgcn_wave_barrier();

    const float* xwp = xw0T + (size_t)b * (Hsz * Ssz) + (size_t)((g == 0) ? i : 0) * Ssz;
    float*       hop = h2T  + (size_t)b * (Hsz * Ssz) + (size_t)((g == 2) ? i : 0) * Ssz;

    float4 cur = *(const float4*)(xwp + 0);
    float4 nxt = *(const float4*)(xwp + 4);

    // 2052 ticks (need S+2 = 2050); xw prefetched 8 ticks ahead.
    for (int tb = 0; tb < Ssz + 4; tb += 4) {
        int tl = tb + 8; if (tl > Ssz - 4) tl = Ssz - 4;
        float4 fut = *(const float4*)(xwp + tl);
        float ev[4] = {cur.x, cur.y, cur.z, cur.w};
#pragma unroll
        for (int u = 0; u < 4; ++u) {
            const int T = tb + u;
            float e = (g == 0) ? ev[u] : econst;

            const float4* sx4 = (const float4*)(sbuf + xbase);
            const float4* sh4 = (const float4*)(sbuf + hbase);
            float4 qa = sx4[0], qb = sx4[1], qc = sx4[2], qd = sx4[3];
            float2 qe = *(const float2*)(sbuf + xbase + 16);
            float4 pa = sh4[0], pb = sh4[1], pc = sh4[2], pd = sh4[3];
            float2 pe = *(const float2*)(sbuf + hbase + 16);
            float xv[18] = {qa.x,qa.y,qa.z,qa.w, qb.x,qb.y,qb.z,qb.w,
                            qc.x,qc.y,qc.z,qc.w, qd.x,qd.y,qd.z,qd.w, qe.x,qe.y};
            float hv[18] = {pa.x,pa.y,pa.z,pa.w, pb.x,pb.y,pb.z,pb.w,
                            pc.x,pc.y,pc.z,pc.w, pd.x,pd.y,pd.z,pd.w, pe.x,pe.y};

            float a0 = e, a1 = 0.0f, a2 = 0.0f, a3 = 0.0f;
#pragma unroll
            for (int j = 0; j < 18; j += 2) {
                a0 = fmaf(wx[j],     xv[j],     a0);
                a1 = fmaf(wx[j + 1], xv[j + 1], a1);
                a2 = fmaf(wh[j],     hv[j],     a2);
                a3 = fmaf(wh[j + 1], hv[j + 1], a3);
            }
            float tot = (a0 + a1) + (a2 + a3);
            float nh = tanh_fast(tot);
            bool upd = lane_active && (T >= g) && (T < Ssz + g);
            h = upd ? nh : h;
            sbuf[slot] = h;
            if (g == 2 && upd) hop[T - 2] = h;
            __builtin_amdgcn_wave_barrier();
        }
        cur = nxt; nxt = fut;
    }

    if (lane_active) hid_out[(g * Bsz + b) * Hsz + i] = h;
}

// K3: MLP head 18->18->10->8->4->2->1, one thread per (b,t).
__global__ __launch_bounds__(256) void mlp_head(
    const float* __restrict__ h2T,
    const float* __restrict__ W1, const float* __restrict__ b1,
    const float* __restrict__ W2, const float* __restrict__ b2,
    const float* __restrict__ W3, const float* __restrict__ b3,
    const float* __restrict__ W4, const float* __restrict__ b4,
    const float* __restrict__ W5, const float* __restrict__ b5,
    const float* __restrict__ W6, const float* __restrict__ b6,
    float* __restrict__ out)
{
    int idx = blockIdx.x * 256 + threadIdx.x;  // = b*S + t
    int b = idx >> 11;
    int t = idx & (Ssz - 1);
    const float* hp = h2T + (size_t)b * (Hsz * Ssz) + t;
    float v[Hsz];
#pragma unroll
    for (int j = 0; j < Hsz; ++j) v[j] = hp[(size_t)j * Ssz];

    float a1[18];
#pragma unroll
    for (int o = 0; o < 18; ++o) {
        float acc = b1[o];
#pragma unroll
        for (int j = 0; j < 18; ++j) acc = fmaf(W1[o * 18 + j], v[j], acc);
        a1[o] = fmaxf(acc, 0.0f);
    }
    float a2[10];
#pragma unroll
    for (int o = 0; o < 10; ++o) {
        float acc = b2[o];
#pragma unroll
        for (int j = 0; j < 18; ++j) acc = fmaf(W2[o * 18 + j], a1[j], acc);
        a2[o] = fmaxf(acc, 0.0f);
    }
    float a3[8];
#pragma unroll
    for (int o = 0; o < 8; ++o) {
        float acc = b3[o];
#pragma unroll
        for (int j = 0; j < 10; ++j) acc = fmaf(W3[o * 10 + j], a2[j], acc);
        a3[o] = fmaxf(acc, 0.0f);
    }
    float a4[4];
#pragma unroll
    for (int o = 0; o < 4; ++o) {
        float acc = b4[o];
#pragma unroll
        for (int j = 0; j < 8; ++j) acc = fmaf(W4[o * 8 + j], a3[j], acc);
        a4[o] = fmaxf(acc, 0.0f);
    }
    float a5[2];
#pragma unroll
    for (int o = 0; o < 2; ++o) {
        float acc = b5[o];
#pragma unroll
        for (int j = 0; j < 4; ++j) acc = fmaf(W5[o * 4 + j], a4[j], acc);
        a5[o] = fmaxf(acc, 0.0f);
    }
    float r6 = b6[0];
    r6 = fmaf(W6[0], a5[0], r6);
    r6 = fmaf(W6[1], a5[1], r6);
    out[idx] = r6;
}

extern "C" void kernel_launch(void* const* d_in, const int* in_sizes, int n_in,
                              void* d_out, int out_size, void* d_ws, size_t ws_size,
                              hipStream_t stream) {
    (void)in_sizes; (void)n_in; (void)out_size; (void)ws_size;
    const float* input  = (const float*)d_in[0];
    const float* hidden = (const float*)d_in[1];
    const float* Wih0 = (const float*)d_in[2];  const float* bih0 = (const float*)d_in[3];
    const float* Whh0 = (const float*)d_in[4];  const float* bhh0 = (const float*)d_in[5];
    const float* Wih1 = (const float*)d_in[6];  const float* bih1 = (const float*)d_in[7];
    const float* Whh1 = (const float*)d_in[8];  const float* bhh1 = (const float*)d_in[9];
    const float* Wih2 = (const float*)d_in[10]; const float* bih2 = (const float*)d_in[11];
    const float* Whh2 = (const float*)d_in[12]; const float* bhh2 = (const float*)d_in[13];
    const float* W1 = (const float*)d_in[14]; const float* b1 = (const float*)d_in[15];
    const float* W2 = (const float*)d_in[16]; const float* b2 = (const float*)d_in[17];
    const float* W3 = (const float*)d_in[18]; const float* b3 = (const float*)d_in[19];
    const float* W4 = (const float*)d_in[20]; const float* b4 = (const float*)d_in[21];
    const float* W5 = (const float*)d_in[22]; const float* b5 = (const float*)d_in[23];
    const float* W6 = (const float*)d_in[24]; const float* b6 = (const float*)d_in[25];

    float* xw0T = (float*)d_ws;                         // [B][18][S] = 37.75 MB
    float* h2T  = xw0T + (size_t)Bsz * Hsz * Ssz;       // [B][18][S] = 37.75 MB
    float* out  = (float*)d_out;                        // [B*S]
    float* hout = out + (size_t)Bsz * Ssz;              // [3][B][18]

    input_gemm<<<dim3(2048), dim3(256), 0, stream>>>(input, Wih0, bih0, bhh0, xw0T);
    rnn_scan<<<dim3(256), dim3(64), 0, stream>>>(xw0T, hidden, Whh0,
                                                 Wih1, bih1, Whh1, bhh1,
                                                 Wih2, bih2, Whh2, bhh2,
                                                 h2T, hout);
    mlp_head<<<dim3(2048), dim3(256), 0, stream>>>(h2T, W1, b1, W2, b2, W3, b3,
                                                   W4, b4, W5, b5, W6, b6, out);
}

// Round 2
// 512.629 us; speedup vs baseline: 1.2249x; 1.2249x over previous
//
#include <hip/hip_runtime.h>

#define Bsz 256
#define Ssz 2048
#define Isz 32
#define Hsz 18

typedef float f2 __attribute__((ext_vector_type(2)));
typedef float f4 __attribute__((ext_vector_type(4)));

__device__ __forceinline__ float tanh_fast(float x) {
    // tanh(x) = 1 - 2/(e^{2x}+1); saturates correctly at +/-inf
    float t = __expf(2.0f * x);
    float r = __builtin_amdgcn_rcpf(t + 1.0f);
    return fmaf(-2.0f, r, 1.0f);
}

// K1: xw0T[b][i][t] = sum_k input[b][t][k] * Wih0[i][k] + bih0[i] + bhh0[i]
// LDS transpose (pad 33 -> conflict-free) to keep global reads coalesced.
__global__ __launch_bounds__(256) void input_gemm(
    const float* __restrict__ x,
    const float* __restrict__ Wih0,
    const float* __restrict__ bih0,
    const float* __restrict__ bhh0,
    float* __restrict__ xw0T)
{
    __shared__ float xs[256 * 33];
    int blk = blockIdx.x;                  // 2048 blocks
    int b = blk >> 3;
    int t0 = (blk & 7) << 8;
    int tid = threadIdx.x;

    const float4* src = (const float4*)(x + ((size_t)b * Ssz + t0) * Isz);
#pragma unroll
    for (int k = 0; k < 8; ++k) {
        int l = k * 256 + tid;             // coalesced float4 index
        float4 v = src[l];
        int row = l >> 3, k4 = l & 7;
        float* p = xs + row * 33 + k4 * 4;
        p[0] = v.x; p[1] = v.y; p[2] = v.z; p[3] = v.w;
    }
    __syncthreads();

    float xv[32];
    const float* myrow = xs + tid * 33;
#pragma unroll
    for (int k = 0; k < 32; ++k) xv[k] = myrow[k];

    float* op = xw0T + (size_t)b * (Hsz * Ssz) + (t0 + tid);
#pragma unroll
    for (int ii = 0; ii < Hsz; ++ii) {
        float acc = bih0[ii] + bhh0[ii];
#pragma unroll
        for (int k = 0; k < 32; ++k) acc = fmaf(xv[k], Wih0[ii * Isz + k], acc);
        op[(size_t)ii * Ssz] = acc;
    }
}

// K2: pipelined 3-layer scan as a 54-wide recurrence. One wave per batch.
// Lane r = 18*g + i owns (layer g, unit i). State exchanged via LDS each tick.
// Group g at tick T computes h_g[t = T - g].
__global__ __launch_bounds__(64) void rnn_scan(
    const float* __restrict__ xw0T,
    const float* __restrict__ hidden,
    const float* __restrict__ Whh0,
    const float* __restrict__ Wih1, const float* __restrict__ bih1,
    const float* __restrict__ Whh1, const float* __restrict__ bhh1,
    const float* __restrict__ Wih2, const float* __restrict__ bih2,
    const float* __restrict__ Whh2, const float* __restrict__ bhh2,
    float* __restrict__ h2T,
    float* __restrict__ hid_out)
{
    const int b = blockIdx.x;
    const int r = threadIdx.x;
    const int g = (r < 18) ? 0 : (r < 36) ? 1 : (r < 54) ? 2 : 3;
    const int i = r - g * 18;
    const bool lane_active = (g < 3);
    const bool g2lane = (g == 2);

    __shared__ __align__(16) float sbuf[176];
    for (int k = r; k < 176; k += 64) sbuf[k] = 0.0f;

    float wh[Hsz], wx[Hsz];
    float econst = 0.0f;
    float h = 0.0f;
    if (lane_active) {
        const float* Whh = (g == 0) ? Whh0 : (g == 1) ? Whh1 : Whh2;
#pragma unroll
        for (int j = 0; j < Hsz; ++j) wh[j] = Whh[i * Hsz + j];
        if (g >= 1) {
            const float* Wih = (g == 1) ? Wih1 : Wih2;
            const float* bi  = (g == 1) ? bih1 : bih2;
            const float* bh  = (g == 1) ? bhh1 : bhh2;
#pragma unroll
            for (int j = 0; j < Hsz; ++j) wx[j] = Wih[i * Hsz + j];
            econst = bi[i] + bh[i];
        } else {
#pragma unroll
            for (int j = 0; j < Hsz; ++j) wx[j] = 0.0f;
        }
        h = hidden[(g * Bsz + b) * Hsz + i];
    } else {
#pragma unroll
        for (int j = 0; j < Hsz; ++j) { wh[j] = 0.0f; wx[j] = 0.0f; }
    }

    // pack weights to f2 for v_pk_fma_f32
    f2 wx2[9], wh2[9];
#pragma unroll
    for (int k = 0; k < 9; ++k) {
        wx2[k] = f2{wx[2 * k], wx[2 * k + 1]};
        wh2[k] = f2{wh[2 * k], wh[2 * k + 1]};
    }

    const int slot  = 36 + 36 * g + i;   // g==3 dump region stays harmless
    const int xbase = 36 * g;            // previous group's state (g0 reads zeros)
    const int hbase = 36 * g + 36;       // own group's state

    sbuf[slot] = h;
    __builtin_amdgcn_wave_barrier();

    const float* xwp = xw0T + (size_t)b * (Hsz * Ssz) + (size_t)((g == 0) ? i : 0) * Ssz;
    float*       hop2 = h2T + (size_t)b * (Hsz * Ssz) + (size_t)i * Ssz; // used by g2 only

    float4 cur = *(const float4*)(xwp + 0);
    float4 nxt = *(const float4*)(xwp + 4);
    float4 ob;  // g2 output buffer; slot for t is ob[t&3]

    const f4* sx4 = (const f4*)(sbuf + xbase);
    const f4* sh4 = (const f4*)(sbuf + hbase);
    const f2* sx2 = (const f2*)(sbuf + xbase + 16);
    const f2* sh2 = (const f2*)(sbuf + hbase + 16);

    // one tick: reads -> packed dot -> tanh. Returns new h candidate.
    auto tick_core = [&](float e) -> float {
        f4 qa = sx4[0], qb = sx4[1], qc = sx4[2], qd = sx4[3];
        f2 qe = sx2[0];
        f4 pa = sh4[0], pb = sh4[1], pc = sh4[2], pd = sh4[3];
        f2 pe = sh2[0];
        f2 xs2[9] = {
            __builtin_shufflevector(qa, qa, 0, 1), __builtin_shufflevector(qa, qa, 2, 3),
            __builtin_shufflevector(qb, qb, 0, 1), __builtin_shufflevector(qb, qb, 2, 3),
            __builtin_shufflevector(qc, qc, 0, 1), __builtin_shufflevector(qc, qc, 2, 3),
            __builtin_shufflevector(qd, qd, 0, 1), __builtin_shufflevector(qd, qd, 2, 3),
            qe };
        f2 hs2[9] = {
            __builtin_shufflevector(pa, pa, 0, 1), __builtin_shufflevector(pa, pa, 2, 3),
            __builtin_shufflevector(pb, pb, 0, 1), __builtin_shufflevector(pb, pb, 2, 3),
            __builtin_shufflevector(pc, pc, 0, 1), __builtin_shufflevector(pc, pc, 2, 3),
            __builtin_shufflevector(pd, pd, 0, 1), __builtin_shufflevector(pd, pd, 2, 3),
            pe };
        f2 ax0 = f2{0.0f, 0.0f}, ax1 = f2{0.0f, 0.0f};
        f2 ah0 = f2{0.0f, 0.0f}, ah1 = f2{0.0f, 0.0f};
#pragma unroll
        for (int k = 0; k < 8; k += 2) {
            ax0 = __builtin_elementwise_fma(wx2[k],     xs2[k],     ax0);
            ax1 = __builtin_elementwise_fma(wx2[k + 1], xs2[k + 1], ax1);
            ah0 = __builtin_elementwise_fma(wh2[k],     hs2[k],     ah0);
            ah1 = __builtin_elementwise_fma(wh2[k + 1], hs2[k + 1], ah1);
        }
        ax0 = __builtin_elementwise_fma(wx2[8], xs2[8], ax0);
        ah0 = __builtin_elementwise_fma(wh2[8], hs2[8], ah0);
        f2 s = (ax0 + ax1) + (ah0 + ah1);
        return tanh_fast(s.x + s.y + e);
    };

    // ---- prologue block: T = 0..3, masked updates ----
    {
        float4 fut = *(const float4*)(xwp + 8);
        float ev[4] = {cur.x, cur.y, cur.z, cur.w};
#pragma unroll
        for (int u = 0; u < 4; ++u) {
            const int T = u;
            float e = (g == 0) ? ev[u] : econst;
            float nh = tick_core(e);
            bool upd = lane_active && (T >= g);
            h = upd ? nh : h;
            sbuf[slot] = h;
            if (u == 2) ob.x = h; else if (u == 3) ob.y = h;
            __builtin_amdgcn_wave_barrier();
        }
        cur = nxt; nxt = fut;
    }

    // ---- interior blocks: T = 4..2047, no masking, no per-tick stores ----
    for (int tb = 4; tb < Ssz; tb += 4) {
        int tl = tb + 8; if (tl > Ssz - 4) tl = Ssz - 4;
        float4 fut = *(const float4*)(xwp + tl);
        float ev[4] = {cur.x, cur.y, cur.z, cur.w};
#pragma unroll
        for (int u = 0; u < 4; ++u) {
            float e = (g == 0) ? ev[u] : econst;
            h = tick_core(e);        // idle lanes compute tanh(0)=0 harmlessly
            sbuf[slot] = h;
            if (u == 0) ob.z = h;
            else if (u == 1) { ob.w = h; if (g2lane) *(float4*)(hop2 + tb - 4) = *(float4*)&ob; }
            else if (u == 2) ob.x = h;
            else ob.y = h;
            __builtin_amdgcn_wave_barrier();
        }
        cur = nxt; nxt = fut;
    }

    // ---- tail block: T = 2048..2051, masked (freeze finished groups) ----
    {
        float ev[4] = {cur.x, cur.y, cur.z, cur.w};
#pragma unroll
        for (int u = 0; u < 4; ++u) {
            const int T = Ssz + u;
            float e = (g == 0) ? ev[u] : econst;
            float nh = tick_core(e);
            bool upd = lane_active && (T <= Ssz - 1 + g);
            h = upd ? nh : h;
            sbuf[slot] = h;
            if (u == 0) ob.z = h;
            else if (u == 1) { ob.w = h; if (g2lane) *(float4*)(hop2 + Ssz - 4) = *(float4*)&ob; }
            __builtin_amdgcn_wave_barrier();
        }
    }

    if (lane_active) hid_out[(g * Bsz + b) * Hsz + i] = h;
}

// K3: MLP head 18->18->10->8->4->2->1, one thread per (b,t).
__global__ __launch_bounds__(256) void mlp_head(
    const float* __restrict__ h2T,
    const float* __restrict__ W1, const float* __restrict__ b1,
    const float* __restrict__ W2, const float* __restrict__ b2,
    const float* __restrict__ W3, const float* __restrict__ b3,
    const float* __restrict__ W4, const float* __restrict__ b4,
    const float* __restrict__ W5, const float* __restrict__ b5,
    const float* __restrict__ W6, const float* __restrict__ b6,
    float* __restrict__ out)
{
    int idx = blockIdx.x * 256 + threadIdx.x;  // = b*S + t
    int b = idx >> 11;
    int t = idx & (Ssz - 1);
    const float* hp = h2T + (size_t)b * (Hsz * Ssz) + t;
    float v[Hsz];
#pragma unroll
    for (int j = 0; j < Hsz; ++j) v[j] = hp[(size_t)j * Ssz];

    float a1[18];
#pragma unroll
    for (int o = 0; o < 18; ++o) {
        float acc = b1[o];
#pragma unroll
        for (int j = 0; j < 18; ++j) acc = fmaf(W1[o * 18 + j], v[j], acc);
        a1[o] = fmaxf(acc, 0.0f);
    }
    float a2[10];
#pragma unroll
    for (int o = 0; o < 10; ++o) {
        float acc = b2[o];
#pragma unroll
        for (int j = 0; j < 18; ++j) acc = fmaf(W2[o * 18 + j], a1[j], acc);
        a2[o] = fmaxf(acc, 0.0f);
    }
    float a3[8];
#pragma unroll
    for (int o = 0; o < 8; ++o) {
        float acc = b3[o];
#pragma unroll
        for (int j = 0; j < 10; ++j) acc = fmaf(W3[o * 10 + j], a2[j], acc);
        a3[o] = fmaxf(acc, 0.0f);
    }
    float a4[4];
#pragma unroll
    for (int o = 0; o < 4; ++o) {
        float acc = b4[o];
#pragma unroll
        for (int j = 0; j < 8; ++j) acc = fmaf(W4[o * 8 + j], a3[j], acc);
        a4[o] = fmaxf(acc, 0.0f);
    }
    float a5[2];
#pragma unroll
    for (int o = 0; o < 2; ++o) {
        float acc = b5[o];
#pragma unroll
        for (int j = 0; j < 4; ++j) acc = fmaf(W5[o * 4 + j], a4[j], acc);
        a5[o] = fmaxf(acc, 0.0f);
    }
    float r6 = b6[0];
    r6 = fmaf(W6[0], a5[0], r6);
    r6 = fmaf(W6[1], a5[1], r6);
    out[idx] = r6;
}

extern "C" void kernel_launch(void* const* d_in, const int* in_sizes, int n_in,
                              void* d_out, int out_size, void* d_ws, size_t ws_size,
                              hipStream_t stream) {
    (void)in_sizes; (void)n_in; (void)out_size; (void)ws_size;
    const float* input  = (const float*)d_in[0];
    const float* hidden = (const float*)d_in[1];
    const float* Wih0 = (const float*)d_in[2];  const float* bih0 = (const float*)d_in[3];
    const float* Whh0 = (const float*)d_in[4];  const float* bhh0 = (const float*)d_in[5];
    const float* Wih1 = (const float*)d_in[6];  const float* bih1 = (const float*)d_in[7];
    const float* Whh1 = (const float*)d_in[8];  const float* bhh1 = (const float*)d_in[9];
    const float* Wih2 = (const float*)d_in[10]; const float* bih2 = (const float*)d_in[11];
    const float* Whh2 = (const float*)d_in[12]; const float* bhh2 = (const float*)d_in[13];
    const float* W1 = (const float*)d_in[14]; const float* b1 = (const float*)d_in[15];
    const float* W2 = (const float*)d_in[16]; const float* b2 = (const float*)d_in[17];
    const float* W3 = (const float*)d_in[18]; const float* b3 = (const float*)d_in[19];
    const float* W4 = (const float*)d_in[20]; const float* b4 = (const float*)d_in[21];
    const float* W5 = (const float*)d_in[22]; const float* b5 = (const float*)d_in[23];
    const float* W6 = (const float*)d_in[24]; const float* b6 = (const float*)d_in[25];

    float* xw0T = (float*)d_ws;                         // [B][18][S]
    float* h2T  = xw0T + (size_t)Bsz * Hsz * Ssz;       // [B][18][S]
    float* out  = (float*)d_out;                        // [B*S]
    float* hout = out + (size_t)Bsz * Ssz;              // [3][B][18]

    input_gemm<<<dim3(2048), dim3(256), 0, stream>>>(input, Wih0, bih0, bhh0, xw0T);
    rnn_scan<<<dim3(256), dim3(64), 0, stream>>>(xw0T, hidden, Whh0,
                                                 Wih1, bih1, Whh1, bhh1,
                                                 Wih2, bih2, Whh2, bhh2,
                                                 h2T, hout);
    mlp_head<<<dim3(2048), dim3(256), 0, stream>>>(h2T, W1, b1, W2, b2, W3, b3,
                                                   W4, b4, W5, b5, W6, b6, out);
}

// Round 3
// 441.328 us; speedup vs baseline: 1.4228x; 1.1616x over previous
//
#include <hip/hip_runtime.h>

#define Bsz 256
#define Ssz 2048
#define Isz 32
#define Hsz 18
#define SCALE 2.885390081777927f   // 2*log2(e): pre-scales all pre-activations

typedef float f2 __attribute__((ext_vector_type(2)));
typedef float f4 __attribute__((ext_vector_type(4)));

#define LO2(v) __builtin_shufflevector(v, v, 0, 1)
#define HI2(v) __builtin_shufflevector(v, v, 2, 3)

__device__ __forceinline__ float exp2_fast(float x) {
#if __has_builtin(__builtin_amdgcn_exp2f)
    return __builtin_amdgcn_exp2f(x);
#else
    return __expf(x * 0.6931471805599453f);
#endif
}

// K1: xw0T[b][i][t] = SCALE * (sum_k input[b][t][k]*Wih0[i][k] + bih0[i] + bhh0[i])
// LDS transpose (pad 33 -> conflict-free) keeps global reads coalesced.
__global__ __launch_bounds__(256) void input_gemm(
    const float* __restrict__ x,
    const float* __restrict__ Wih0,
    const float* __restrict__ bih0,
    const float* __restrict__ bhh0,
    float* __restrict__ xw0T)
{
    __shared__ float xs[256 * 33];
    int blk = blockIdx.x;                  // 2048 blocks
    int b = blk >> 3;
    int t0 = (blk & 7) << 8;
    int tid = threadIdx.x;

    const float4* src = (const float4*)(x + ((size_t)b * Ssz + t0) * Isz);
#pragma unroll
    for (int k = 0; k < 8; ++k) {
        int l = k * 256 + tid;             // coalesced float4 index
        float4 v = src[l];
        int row = l >> 3, k4 = l & 7;
        float* p = xs + row * 33 + k4 * 4;
        p[0] = v.x; p[1] = v.y; p[2] = v.z; p[3] = v.w;
    }
    __syncthreads();

    float xv[32];
    const float* myrow = xs + tid * 33;
#pragma unroll
    for (int k = 0; k < 32; ++k) xv[k] = myrow[k];

    float* op = xw0T + (size_t)b * (Hsz * Ssz) + (t0 + tid);
#pragma unroll
    for (int ii = 0; ii < Hsz; ++ii) {
        float acc = bih0[ii] + bhh0[ii];
#pragma unroll
        for (int k = 0; k < 32; ++k) acc = fmaf(xv[k], Wih0[ii * Isz + k], acc);
        op[(size_t)ii * Ssz] = acc * SCALE;
    }
}

// K2: pipelined 3-layer scan as a 54-wide recurrence. One wave per batch.
// Lane r = 18*g + i owns (layer g, unit i). State exchanged via LDS each tick.
// Group g at tick T computes h_g[t = T - g]. All pre-activations carry SCALE;
// tanh(x) = 1 - 2/(exp2(SCALE*x)+1).
__global__ __launch_bounds__(64) void rnn_scan(
    const float* __restrict__ xw0T,
    const float* __restrict__ hidden,
    const float* __restrict__ Whh0,
    const float* __restrict__ Wih1, const float* __restrict__ bih1,
    const float* __restrict__ Whh1, const float* __restrict__ bhh1,
    const float* __restrict__ Wih2, const float* __restrict__ bih2,
    const float* __restrict__ Whh2, const float* __restrict__ bhh2,
    float* __restrict__ h2T,
    float* __restrict__ hid_out)
{
    const int b = blockIdx.x;
    const int r = threadIdx.x;
    const int g = (r < 18) ? 0 : (r < 36) ? 1 : (r < 54) ? 2 : 3;
    const int i = r - g * 18;
    const bool lane_active = (g < 3);
    const bool g0lane = (g == 0);
    const bool g2lane = (g == 2);

    // group stride 36 floats (144B, 16B-aligned). [0..35] stays zero (g0's x-src).
    __shared__ __align__(16) float sbuf[176];
    for (int k = r; k < 176; k += 64) sbuf[k] = 0.0f;

    float wx[Hsz], wh[Hsz];
    float econst = 0.0f;
    float h = 0.0f;
    if (lane_active) {
        const float* Whh = (g == 0) ? Whh0 : (g == 1) ? Whh1 : Whh2;
#pragma unroll
        for (int j = 0; j < Hsz; ++j) wh[j] = Whh[i * Hsz + j] * SCALE;
        if (g >= 1) {
            const float* Wih = (g == 1) ? Wih1 : Wih2;
            const float* bi  = (g == 1) ? bih1 : bih2;
            const float* bh  = (g == 1) ? bhh1 : bhh2;
#pragma unroll
            for (int j = 0; j < Hsz; ++j) wx[j] = Wih[i * Hsz + j] * SCALE;
            econst = (bi[i] + bh[i]) * SCALE;
        } else {
#pragma unroll
            for (int j = 0; j < Hsz; ++j) wx[j] = 0.0f;
        }
        h = hidden[(g * Bsz + b) * Hsz + i];
    } else {
#pragma unroll
        for (int j = 0; j < Hsz; ++j) { wx[j] = 0.0f; wh[j] = 0.0f; }
    }

    f2 wx2[9], wh2[9];
#pragma unroll
    for (int k = 0; k < 9; ++k) {
        wx2[k] = f2{wx[2 * k], wx[2 * k + 1]};
        wh2[k] = f2{wh[2 * k], wh[2 * k + 1]};
    }

    const int slot  = 36 + 36 * g + i;   // g==3 dump region 144..153
    const int xbase = 36 * g;            // previous group's state
    const int hbase = 36 * g + 36;       // own group's state

    sbuf[slot] = h;
    __builtin_amdgcn_wave_barrier();

    const float* xwp = xw0T + (size_t)b * (Hsz * Ssz) + (size_t)((g == 0) ? i : 0) * Ssz;
    float*       hop2 = h2T + (size_t)b * (Hsz * Ssz) + (size_t)i * Ssz; // g2 only

    const f4* sx4 = (const f4*)(sbuf + xbase);
    const f4* sh4 = (const f4*)(sbuf + hbase);
    const f2* sx2 = (const f2*)(sbuf + xbase + 16);
    const f2* sh2 = (const f2*)(sbuf + hbase + 16);

    f4 cur = *(const f4*)(xwp + 0);
    f4 nxt = *(const f4*)(xwp + 4);
    f4 ob;  // g2 output buffer: {t0,t1,t2,t3} of a 4-aligned time quad

    // One tick: issue reads, (optionally flush ob off-chain), dot, tanh.
    auto do_tick = [&](float e, bool dostore, int st) -> float {
        f4 qa = sx4[0], qb = sx4[1], qc = sx4[2], qd = sx4[3];
        f2 qe = sx2[0];
        f4 pa = sh4[0], pb = sh4[1], pc = sh4[2], pd = sh4[3];
        f2 pe = sh2[0];
        if (dostore && g2lane) *(f4*)(hop2 + st) = ob;   // off the dep chain
        f2 ax0 = f2{e, 0.0f}, ax1 = f2{0.0f, 0.0f}, ax2 = f2{0.0f, 0.0f};
        f2 ah0 = f2{0.0f, 0.0f}, ah1 = f2{0.0f, 0.0f}, ah2 = f2{0.0f, 0.0f};
        ax0 = __builtin_elementwise_fma(wx2[0], LO2(qa), ax0);
        ax1 = __builtin_elementwise_fma(wx2[1], HI2(qa), ax1);
        ax2 = __builtin_elementwise_fma(wx2[2], LO2(qb), ax2);
        ah0 = __builtin_elementwise_fma(wh2[0], LO2(pa), ah0);
        ah1 = __builtin_elementwise_fma(wh2[1], HI2(pa), ah1);
        ah2 = __builtin_elementwise_fma(wh2[2], LO2(pb), ah2);
        ax0 = __builtin_elementwise_fma(wx2[3], HI2(qb), ax0);
        ax1 = __builtin_elementwise_fma(wx2[4], LO2(qc), ax1);
        ax2 = __builtin_elementwise_fma(wx2[5], HI2(qc), ax2);
        ah0 = __builtin_elementwise_fma(wh2[3], HI2(pb), ah0);
        ah1 = __builtin_elementwise_fma(wh2[4], LO2(pc), ah1);
        ah2 = __builtin_elementwise_fma(wh2[5], HI2(pc), ah2);
        ax0 = __builtin_elementwise_fma(wx2[6], LO2(qd), ax0);
        ax1 = __builtin_elementwise_fma(wx2[7], HI2(qd), ax1);
        ax2 = __builtin_elementwise_fma(wx2[8], qe,      ax2);
        ah0 = __builtin_elementwise_fma(wh2[6], LO2(pd), ah0);
        ah1 = __builtin_elementwise_fma(wh2[7], HI2(pd), ah1);
        ah2 = __builtin_elementwise_fma(wh2[8], pe,      ah2);
        f2 t0 = ax0 + ax1, t1 = ax2 + ah0, t2 = ah1 + ah2;
        f2 s = (t0 + t1) + t2;
        float a = s.x + s.y;
        float t = exp2_fast(a);
        return fmaf(-2.0f, __builtin_amdgcn_rcpf(t + 1.0f), 1.0f);
    };

    // ---- prologue: T = 0..3, masked updates, no store ----
    {
        f4 fut = *(const f4*)(xwp + 8);
        float ev[4] = {cur.x, cur.y, cur.z, cur.w};
#pragma unroll
        for (int u = 0; u < 4; ++u) {
            const int T = u;
            float e = g0lane ? ev[u] : econst;
            float nh = do_tick(e, false, 0);
            bool upd = lane_active && (T >= g);
            h = upd ? nh : h;
            sbuf[slot] = h;
            if (u == 2) ob.x = h; else if (u == 3) ob.y = h;
            __builtin_amdgcn_wave_barrier();
        }
        cur = nxt; nxt = fut;
    }

    // ---- interior: T = 4..2047, unmasked; g2 flush at u==2 (t quad tb-4..tb-1) ----
    for (int tb = 4; tb < Ssz; tb += 4) {
        int tl = tb + 8; if (tl > Ssz - 4) tl = Ssz - 4;
        f4 fut = *(const f4*)(xwp + tl);
        float ev[4] = {cur.x, cur.y, cur.z, cur.w};
#pragma unroll
        for (int u = 0; u < 4; ++u) {
            float e = g0lane ? ev[u] : econst;
            h = do_tick(e, u == 2, tb - 4);  // idle lanes: tanh(0)=0, harmless
            sbuf[slot] = h;
            if (u == 0) ob.z = h;
            else if (u == 1) ob.w = h;
            else if (u == 2) ob.x = h;
            else ob.y = h;
            __builtin_amdgcn_wave_barrier();
        }
        cur = nxt; nxt = fut;
    }

    // ---- tail: T = 2048..2049 (minimum needed), masked ----
    {
        float ev[4] = {cur.x, cur.y, cur.z, cur.w};
#pragma unroll
        for (int u = 0; u < 2; ++u) {
            const int T = Ssz + u;
            float e = g0lane ? ev[u] : econst;
            float nh = do_tick(e, false, 0);
            bool upd = lane_active && (T <= Ssz - 1 + g);
            h = upd ? nh : h;
            sbuf[slot] = h;
            if (u == 0) ob.z = h; else ob.w = h;
            __builtin_amdgcn_wave_barrier();
        }
        if (g2lane) *(f4*)(hop2 + Ssz - 4) = ob;  // final quad t=2044..2047
    }

    if (lane_active) hid_out[(g * Bsz + b) * Hsz + i] = h;
}

// K3: MLP head 18->18->10->8->4->2->1, one thread per (b,t).
__global__ __launch_bounds__(256) void mlp_head(
    const float* __restrict__ h2T,
    const float* __restrict__ W1, const float* __restrict__ b1,
    const float* __restrict__ W2, const float* __restrict__ b2,
    const float* __restrict__ W3, const float* __restrict__ b3,
    const float* __restrict__ W4, const float* __restrict__ b4,
    const float* __restrict__ W5, const float* __restrict__ b5,
    const float* __restrict__ W6, const float* __restrict__ b6,
    float* __restrict__ out)
{
    int idx = blockIdx.x * 256 + threadIdx.x;  // = b*S + t
    int b = idx >> 11;
    int t = idx & (Ssz - 1);
    const float* hp = h2T + (size_t)b * (Hsz * Ssz) + t;
    float v[Hsz];
#pragma unroll
    for (int j = 0; j < Hsz; ++j) v[j] = hp[(size_t)j * Ssz];

    float a1[18];
#pragma unroll
    for (int o = 0; o < 18; ++o) {
        float acc = b1[o];
#pragma unroll
        for (int j = 0; j < 18; ++j) acc = fmaf(W1[o * 18 + j], v[j], acc);
        a1[o] = fmaxf(acc, 0.0f);
    }
    float a2[10];
#pragma unroll
    for (int o = 0; o < 10; ++o) {
        float acc = b2[o];
#pragma unroll
        for (int j = 0; j < 18; ++j) acc = fmaf(W2[o * 18 + j], a1[j], acc);
        a2[o] = fmaxf(acc, 0.0f);
    }
    float a3[8];
#pragma unroll
    for (int o = 0; o < 8; ++o) {
        float acc = b3[o];
#pragma unroll
        for (int j = 0; j < 10; ++j) acc = fmaf(W3[o * 10 + j], a2[j], acc);
        a3[o] = fmaxf(acc, 0.0f);
    }
    float a4[4];
#pragma unroll
    for (int o = 0; o < 4; ++o) {
        float acc = b4[o];
#pragma unroll
        for (int j = 0; j < 8; ++j) acc = fmaf(W4[o * 8 + j], a3[j], acc);
        a4[o] = fmaxf(acc, 0.0f);
    }
    float a5[2];
#pragma unroll
    for (int o = 0; o < 2; ++o) {
        float acc = b5[o];
#pragma unroll
        for (int j = 0; j < 4; ++j) acc = fmaf(W5[o * 4 + j], a4[j], acc);
        a5[o] = fmaxf(acc, 0.0f);
    }
    float r6 = b6[0];
    r6 = fmaf(W6[0], a5[0], r6);
    r6 = fmaf(W6[1], a5[1], r6);
    out[idx] = r6;
}

extern "C" void kernel_launch(void* const* d_in, const int* in_sizes, int n_in,
                              void* d_out, int out_size, void* d_ws, size_t ws_size,
                              hipStream_t stream) {
    (void)in_sizes; (void)n_in; (void)out_size; (void)ws_size;
    const float* input  = (const float*)d_in[0];
    const float* hidden = (const float*)d_in[1];
    const float* Wih0 = (const float*)d_in[2];  const float* bih0 = (const float*)d_in[3];
    const float* Whh0 = (const float*)d_in[4];  const float* bhh0 = (const float*)d_in[5];
    const float* Wih1 = (const float*)d_in[6];  const float* bih1 = (const float*)d_in[7];
    const float* Whh1 = (const float*)d_in[8];  const float* bhh1 = (const float*)d_in[9];
    const float* Wih2 = (const float*)d_in[10]; const float* bih2 = (const float*)d_in[11];
    const float* Whh2 = (const float*)d_in[12]; const float* bhh2 = (const float*)d_in[13];
    const float* W1 = (const float*)d_in[14]; const float* b1 = (const float*)d_in[15];
    const float* W2 = (const float*)d_in[16]; const float* b2 = (const float*)d_in[17];
    const float* W3 = (const float*)d_in[18]; const float* b3 = (const float*)d_in[19];
    const float* W4 = (const float*)d_in[20]; const float* b4 = (const float*)d_in[21];
    const float* W5 = (const float*)d_in[22]; const float* b5 = (const float*)d_in[23];
    const float* W6 = (const float*)d_in[24]; const float* b6 = (const float*)d_in[25];

    float* xw0T = (float*)d_ws;                         // [B][18][S]
    float* h2T  = xw0T + (size_t)Bsz * Hsz * Ssz;       // [B][18][S]
    float* out  = (float*)d_out;                        // [B*S]
    float* hout = out + (size_t)Bsz * Ssz;              // [3][B][18]

    input_gemm<<<dim3(2048), dim3(256), 0, stream>>>(input, Wih0, bih0, bhh0, xw0T);
    rnn_scan<<<dim3(256), dim3(64), 0, stream>>>(xw0T, hidden, Whh0,
                                                 Wih1, bih1, Whh1, bhh1,
                                                 Wih2, bih2, Whh2, bhh2,
                                                 h2T, hout);
    mlp_head<<<dim3(2048), dim3(256), 0, stream>>>(h2T, W1, b1, W2, b2, W3, b3,
                                                   W4, b4, W5, b5, W6, b6, out);
}